// Round 3
// baseline (690.276 us; speedup 1.0000x reference)
//
#include <hip/hip_runtime.h>

// Problem dims
#define TOKS    65536      // 16 * 4096
#define D_IN    512
#define D_E     256
#define NCODES  1024

#define FLAG_CAP 16384
#define TAU      0.05f     // gap threshold for fp32 refinement (~60 sigma of approx err)

using s16x8 = __attribute__((ext_vector_type(8))) short;   // 8 bf16 = 4 VGPRs
using f32x4 = __attribute__((ext_vector_type(4))) float;   // MFMA 16x16 accumulator

__device__ __forceinline__ unsigned short bf16_rne(float x) {
    unsigned u = __float_as_uint(x);
    u += 0x7fffu + ((u >> 16) & 1u);
    return (unsigned short)(u >> 16);
}
__device__ __forceinline__ float bf16_to_f(unsigned short h) {
    return __uint_as_float(((unsigned)h) << 16);
}

// Unpack 8 interleaved (hi<<16|lo) words into separate hi/lo bf16x8 fragments.
__device__ __forceinline__ void unpack_il(uint4 u0, uint4 u1, s16x8& hi, s16x8& lo) {
    union { unsigned u[4]; s16x8 v; } H, L;
    H.u[0] = (u0.y & 0xffff0000u) | (u0.x >> 16);
    H.u[1] = (u0.w & 0xffff0000u) | (u0.z >> 16);
    H.u[2] = (u1.y & 0xffff0000u) | (u1.x >> 16);
    H.u[3] = (u1.w & 0xffff0000u) | (u1.z >> 16);
    L.u[0] = (u0.y << 16) | (u0.x & 0xffffu);
    L.u[1] = (u0.w << 16) | (u0.z & 0xffffu);
    L.u[2] = (u1.y << 16) | (u1.x & 0xffffu);
    L.u[3] = (u1.w << 16) | (u1.z & 0xffffu);
    hi = H.v; lo = L.v;
}

// ---------------------------------------------------------------------------
// Row squared-norm on fp32 rows of 256 (codebook -> cnorm). One wave/row.
// ---------------------------------------------------------------------------
__global__ __launch_bounds__(256) void rownorm_kernel(
        const float* __restrict__ src, float* __restrict__ dst) {
    int row  = blockIdx.x * 4 + (threadIdx.x >> 6);
    int lane = threadIdx.x & 63;
    float4 v = *(const float4*)(src + (long)row * 256 + lane * 4);
    float s = v.x * v.x + v.y * v.y + v.z * v.z + v.w * v.w;
    #pragma unroll
    for (int off = 32; off; off >>= 1) s += __shfl_xor(s, off, 64);
    if (lane == 0) dst[row] = s;
}

// ---------------------------------------------------------------------------
// fp32 -> (hi, lo) bf16 planes. hi = rne(x), lo = rne(x - hi): x to ~2^-17 rel.
// ---------------------------------------------------------------------------
__global__ __launch_bounds__(256) void split_kernel(
        const float* __restrict__ src, unsigned short* __restrict__ hi,
        unsigned short* __restrict__ lo, int n) {
    int i = blockIdx.x * 256 + threadIdx.x;
    if (i < n) {
        float x = src[i];
        unsigned short hb = bf16_rne(x);
        hi[i] = hb;
        lo[i] = bf16_rne(x - bf16_to_f(hb));
    }
}

// ---------------------------------------------------------------------------
// GEMM1 via bf16x3 MFMA: z_e = z @ w_down^T  [65536,512] x [256,512]^T.
// Block = 256 thr / 4 waves, 128 tokens (32/wave as 2 token-tiles of 16).
// z (fp32, HBM, read once) split hi/lo bf16 in-register; w_down planes
// (512 KB, L2-resident) streamed. Epilogue: interleaved z_e planes + znorm.
// ---------------------------------------------------------------------------
__global__ __launch_bounds__(256, 2) void gemm_down_mfma_kernel(
        const float* __restrict__ z, const unsigned short* __restrict__ wd_hi,
        const unsigned short* __restrict__ wd_lo, unsigned* __restrict__ ze_il,
        float* __restrict__ znorm) {
    const int tid  = threadIdx.x;
    const int w    = tid >> 6;
    const int lane = tid & 63;
    const int lr   = lane & 15;
    const int lg   = lane >> 4;
    const int t0   = blockIdx.x * 128 + w * 32;

    f32x4 acc[2][16] = {};   // [token-tile][n-tile]

    #pragma unroll 1
    for (int ks = 0; ks < 16; ++ks) {        // K = 512 in steps of 32
        s16x8 ah[2], al[2];
        #pragma unroll
        for (int tt = 0; tt < 2; ++tt) {
            const float* zp = z + (long)(t0 + tt * 16 + lr) * 512 + ks * 32 + lg * 8;
            float4 x0 = *(const float4*)zp;
            float4 x1 = *(const float4*)(zp + 4);
            float xs[8] = {x0.x, x0.y, x0.z, x0.w, x1.x, x1.y, x1.z, x1.w};
            #pragma unroll
            for (int j = 0; j < 8; ++j) {
                unsigned short hb = bf16_rne(xs[j]);
                ah[tt][j] = (short)hb;
                al[tt][j] = (short)bf16_rne(xs[j] - bf16_to_f(hb));
            }
        }
        #pragma unroll
        for (int nt = 0; nt < 16; ++nt) {
            const long boff = (long)(nt * 16 + lr) * 512 + ks * 32 + lg * 8;
            const s16x8 bh = *(const s16x8*)(wd_hi + boff);
            const s16x8 bl = *(const s16x8*)(wd_lo + boff);
            #pragma unroll
            for (int tt = 0; tt < 2; ++tt) {
                acc[tt][nt] = __builtin_amdgcn_mfma_f32_16x16x32_bf16(al[tt], bh, acc[tt][nt], 0, 0, 0);
                acc[tt][nt] = __builtin_amdgcn_mfma_f32_16x16x32_bf16(ah[tt], bl, acc[tt][nt], 0, 0, 0);
                acc[tt][nt] = __builtin_amdgcn_mfma_f32_16x16x32_bf16(ah[tt], bh, acc[tt][nt], 0, 0, 0);
            }
        }
    }

    // ---- epilogue: interleaved plane write + fused znorm ----
    #pragma unroll
    for (int tt = 0; tt < 2; ++tt) {
        float ns[4] = {0.f, 0.f, 0.f, 0.f};
        #pragma unroll
        for (int nt = 0; nt < 16; ++nt)
            #pragma unroll
            for (int r = 0; r < 4; ++r) {
                float x = acc[tt][nt][r];
                ns[r] += x * x;
                unsigned short hb = bf16_rne(x);
                unsigned short lb = bf16_rne(x - bf16_to_f(hb));
                ze_il[(long)(t0 + tt * 16 + lg * 4 + r) * 256 + nt * 16 + lr] =
                    ((unsigned)hb << 16) | lb;
            }
        #pragma unroll
        for (int r = 0; r < 4; ++r) {
            float s = ns[r];
            s += __shfl_xor(s, 1, 64);
            s += __shfl_xor(s, 2, 64);
            s += __shfl_xor(s, 4, 64);
            s += __shfl_xor(s, 8, 64);
            if (lr == 0) znorm[t0 + tt * 16 + lg * 4 + r] = s;
        }
    }
}

// ---------------------------------------------------------------------------
// Distance + per-half top-2 via bf16x3 MFMA (16x16x32).
// CODE-SPLIT: each block does 128 tokens x 512 codes (half = blockIdx&1)
// -> 1024 blocks = 4 blocks/CU = 16 waves/CU (was grid-starved at 2/CU).
// Codebook chunk staged in LDS with PADDED row stride 136 shorts (272 B):
// bank quad = (row + unit) mod 8 -> uniform 8 lanes/quad, no XOR swizzle,
// static ds_read offsets. Emits {d1,i1,d2,i2} per (token, half) to pair_buf;
// merge_kernel folds halves and owns loss/flag/code writes.
// ---------------------------------------------------------------------------
__global__ __launch_bounds__(256, 2) void argmin_mfma_kernel(
        const unsigned* __restrict__ ze_il,
        const unsigned short* __restrict__ cb_hi, const unsigned short* __restrict__ cb_lo,
        const float* __restrict__ cnorm, int4* __restrict__ pair_buf) {
    __shared__ __align__(16) unsigned short cbs[2][64][136];   // 34 KB, padded stride

    const int tid  = threadIdx.x;
    const int w    = tid >> 6;
    const int lane = tid & 63;
    const int lr   = lane & 15;      // row/col within 16-tile
    const int lg   = lane >> 4;      // k-group (0..3)
    const int t0   = (blockIdx.x >> 1) * 128;
    const int half = blockIdx.x & 1;
    const int cbase = half * 512;

    // ---- load A fragments once: 2 token-tiles x 8 k-steps x {hi,lo} ----
    s16x8 ah[2][8], al[2][8];
    {
        const int tokA = t0 + w * 32 + lr;
        #pragma unroll
        for (int tt = 0; tt < 2; ++tt) {
            const unsigned* pz = ze_il + (long)(tokA + tt * 16) * 256 + lg * 8;
            #pragma unroll
            for (int ks = 0; ks < 8; ++ks) {
                uint4 u0 = *(const uint4*)(pz + ks * 32);
                uint4 u1 = *(const uint4*)(pz + ks * 32 + 4);
                unpack_il(u0, u1, ah[tt][ks], al[tt][ks]);
            }
        }
    }

    const int lane_base = lr * 136 + lg * 8;   // shorts; rest is static offsets

    float d1[8], d2[8];
    int   i1[8], i2[8];
    #pragma unroll
    for (int s = 0; s < 8; ++s) { d1[s] = 3.4e38f; d2[s] = 3.4e38f; i1[s] = 0; i2[s] = 0; }

    #pragma unroll 1
    for (int c = 0; c < 8; ++c) {            // 64-code chunks within this half
        const int c0 = cbase + c * 64;
        f32x4 acc[2][4] = {};

        #pragma unroll
        for (int kc = 0; kc < 2; ++kc) {     // 128-k chunks
            __syncthreads();
            {   // stage cb chunk: wave-pair q picks plane, half the 16B units
                const int r = tid & 63, q = tid >> 6;
                const unsigned short* src = (q & 2 ? cb_lo : cb_hi)
                                            + (c0 + r) * 256 + kc * 128 + (q & 1) * 64;
                unsigned short* dst = &cbs[q >> 1][r][0] + (q & 1) * 64;
                #pragma unroll
                for (int i = 0; i < 8; ++i)
                    *(s16x8*)(dst + i * 8) = *(const s16x8*)(src + i * 8);
            }
            __syncthreads();

            #pragma unroll
            for (int k4 = 0; k4 < 4; ++k4) {
                const int ks = kc * 4 + k4;                 // A reg index (static)
                #pragma unroll
                for (int nt = 0; nt < 4; ++nt) {
                    const int off = lane_base + nt * 2176 + k4 * 32;   // shorts
                    const s16x8 bh = *(const s16x8*)(&cbs[0][0][0] + off);
                    const s16x8 bl = *(const s16x8*)(&cbs[1][0][0] + off);
                    #pragma unroll
                    for (int tt = 0; tt < 2; ++tt) {
                        acc[tt][nt] = __builtin_amdgcn_mfma_f32_16x16x32_bf16(al[tt][ks], bh, acc[tt][nt], 0, 0, 0);
                        acc[tt][nt] = __builtin_amdgcn_mfma_f32_16x16x32_bf16(ah[tt][ks], bl, acc[tt][nt], 0, 0, 0);
                        acc[tt][nt] = __builtin_amdgcn_mfma_f32_16x16x32_bf16(ah[tt][ks], bh, acc[tt][nt], 0, 0, 0);
                    }
                }
            }
        }

        // ---- fold chunk into running top-2 (codes ascend -> strict < keeps first) ----
        #pragma unroll
        for (int nt = 0; nt < 4; ++nt) {
            const int idx = c0 + nt * 16 + lr;
            const float cn = cnorm[idx];
            #pragma unroll
            for (int tt = 0; tt < 2; ++tt)
                #pragma unroll
                for (int r = 0; r < 4; ++r) {
                    float d = cn - 2.0f * acc[tt][nt][r];
                    const int s = tt * 4 + r;
                    if (d < d1[s])      { d2[s] = d1[s]; i2[s] = i1[s]; d1[s] = d; i1[s] = idx; }
                    else if (d < d2[s]) { d2[s] = d;     i2[s] = idx; }
                }
        }
    }

    // ---- cross-lane top-2 merge over the 16 code columns ----
    #pragma unroll
    for (int off = 1; off <= 8; off <<= 1) {
        #pragma unroll
        for (int s = 0; s < 8; ++s) {
            float od1 = __shfl_xor(d1[s], off, 64);
            int   oi1 = __shfl_xor(i1[s], off, 64);
            float od2 = __shfl_xor(d2[s], off, 64);
            int   oi2 = __shfl_xor(i2[s], off, 64);
            bool take = (od1 < d1[s]) || (od1 == d1[s] && oi1 < i1[s]);
            float w1 = take ? od1 : d1[s];  int wi1 = take ? oi1 : i1[s];
            float l1 = take ? d1[s] : od1;  int li1 = take ? i1[s] : oi1;   // loser of firsts
            float w2 = take ? od2 : d2[s];  int wi2 = take ? oi2 : i2[s];   // winner's second
            bool t2 = (l1 < w2) || (l1 == w2 && li1 < wi2);
            d1[s] = w1; i1[s] = wi1;
            d2[s] = t2 ? l1 : w2;
            i2[s] = t2 ? li1 : wi2;
        }
    }

    // ---- emit per-half top-2: lanes lr==0 own tokens (w*32 + tt*16 + lg*4 + r) ----
    if (lr == 0) {
        #pragma unroll
        for (int s = 0; s < 8; ++s) {
            const int tok = t0 + w * 32 + (s >> 2) * 16 + lg * 4 + (s & 3);
            pair_buf[half * TOKS + tok] =
                make_int4(__float_as_int(d1[s]), i1[s], __float_as_int(d2[s]), i2[s]);
        }
    }
}

// ---------------------------------------------------------------------------
// Merge the two code-half top-2 records; write code/loss; flag near-ties.
// Half-0 indices are all < half-1 indices, so strict < preserves the global
// first-index tie-break.
// ---------------------------------------------------------------------------
__global__ __launch_bounds__(256) void merge_kernel(
        const int4* __restrict__ pair_buf, const float* __restrict__ znorm,
        int* __restrict__ code_i, float* __restrict__ code_f,
        float* __restrict__ loss_acc, int* __restrict__ flag_cnt,
        int4* __restrict__ flag_list) {
    const int tok = blockIdx.x * 256 + threadIdx.x;
    const int4 a = pair_buf[tok];
    const int4 b = pair_buf[TOKS + tok];
    const float a1 = __int_as_float(a.x), a2 = __int_as_float(a.z);
    const float b1 = __int_as_float(b.x), b2 = __int_as_float(b.z);

    float d1, d2; int i1, i2;
    if (b1 < a1) {   // half-1 strictly better (ties go to half-0)
        d1 = b1; i1 = b.y;
        if (a1 <= b2) { d2 = a1; i2 = a.y; } else { d2 = b2; i2 = b.w; }
    } else {
        d1 = a1; i1 = a.y;
        if (b1 < a2)  { d2 = b1; i2 = b.y; } else { d2 = a2; i2 = a.w; }
    }

    code_i[tok] = i1;
    code_f[tok] = (float)i1;
    const float rec = d1 + znorm[tok];
    if (d2 - d1 < TAU) {
        int slot = atomicAdd(flag_cnt, 1);
        if (slot < FLAG_CAP)
            flag_list[slot] = make_int4(tok, i1, i2, __float_as_int(rec));
    }
    float lsum = rec;
    #pragma unroll
    for (int off = 32; off; off >>= 1) lsum += __shfl_xor(lsum, off, 64);
    if ((threadIdx.x & 63) == 0)
        atomicAdd(loss_acc + (tok >> 12), lsum);   // 64-tok wave never straddles a batch
}

// ---------------------------------------------------------------------------
// Exact fp32 refinement for near-tie tokens: recompute z_e row from z@w_down
// in fp32, re-decide best-of-two with first-index tie-break, patch loss.
// ---------------------------------------------------------------------------
__global__ __launch_bounds__(256) void refine_kernel(
        const float* __restrict__ z, const float* __restrict__ w_down,
        const float* __restrict__ cb, const int* __restrict__ flag_cnt,
        const int4* __restrict__ flag_list, int* __restrict__ code_i,
        float* __restrict__ code_f, float* __restrict__ loss_acc) {
    __shared__ float zrow[512];
    __shared__ float redA[4], redB[4];
    const int tid = threadIdx.x;
    int n = *flag_cnt;
    if (n > FLAG_CAP) n = FLAG_CAP;

    for (int it = blockIdx.x; it < n; it += gridDim.x) {
        const int4 f = flag_list[it];
        const int tok = f.x, ia = f.y, ib = f.z;
        __syncthreads();
        zrow[tid]       = z[(long)tok * 512 + tid];
        zrow[tid + 256] = z[(long)tok * 512 + 256 + tid];
        __syncthreads();

        // thread e computes z_e[e] = dot(w_down[e], zrow) in fp32
        float s = 0.0f;
        const float* wr = w_down + (long)tid * 512;
        #pragma unroll 4
        for (int k = 0; k < 512; k += 4) {
            float4 a = *(const float4*)(wr + k);
            s += a.x * zrow[k] + a.y * zrow[k + 1] + a.z * zrow[k + 2] + a.w * zrow[k + 3];
        }
        float da = s - cb[(long)ia * 256 + tid]; da *= da;
        float db = s - cb[(long)ib * 256 + tid]; db *= db;
        #pragma unroll
        for (int off = 32; off; off >>= 1) {
            da += __shfl_xor(da, off, 64);
            db += __shfl_xor(db, off, 64);
        }
        if ((tid & 63) == 0) { redA[tid >> 6] = da; redB[tid >> 6] = db; }
        __syncthreads();
        if (tid == 0) {
            float ea = redA[0] + redA[1] + redA[2] + redA[3];
            float eb = redB[0] + redB[1] + redB[2] + redB[3];
            float ebest = ea; int ibest = ia;
            if (eb < ea || (eb == ea && ib < ia)) { ebest = eb; ibest = ib; }
            if (ibest != ia) { code_i[tok] = ibest; code_f[tok] = (float)ibest; }
            atomicAdd(loss_acc + (tok >> 12), ebest - __int_as_float(f.w));
        }
    }
}

// ---------------------------------------------------------------------------
// GEMM2 via bf16x3 MFMA with gather: z_out = cb[code] @ w_up^T.
// No LDS, no barriers: A (gathered cb rows) and B (w_up) fragments stream
// straight from L2. 128 tokens/block, full-K A fragments in registers.
// ---------------------------------------------------------------------------
__global__ __launch_bounds__(256, 2) void gemm_up_mfma_kernel(
        const unsigned short* __restrict__ cb_hi, const unsigned short* __restrict__ cb_lo,
        const unsigned short* __restrict__ wu_hi, const unsigned short* __restrict__ wu_lo,
        const int* __restrict__ code, float* __restrict__ C) {
    const int tid  = threadIdx.x;
    const int w    = tid >> 6;
    const int lane = tid & 63;
    const int lr   = lane & 15;
    const int lg   = lane >> 4;
    const int t0   = blockIdx.x * 128 + w * 32;

    s16x8 ah[2][8], al[2][8];
    #pragma unroll
    for (int tt = 0; tt < 2; ++tt) {
        const int crow = code[t0 + tt * 16 + lr];
        const unsigned short* ph = cb_hi + (long)crow * 256 + lg * 8;
        const unsigned short* pl = cb_lo + (long)crow * 256 + lg * 8;
        #pragma unroll
        for (int ks = 0; ks < 8; ++ks) {
            ah[tt][ks] = *(const s16x8*)(ph + ks * 32);
            al[tt][ks] = *(const s16x8*)(pl + ks * 32);
        }
    }

    #pragma unroll 2
    for (int nt = 0; nt < 32; ++nt) {
        f32x4 acc[2] = {};
        #pragma unroll
        for (int ks = 0; ks < 8; ++ks) {
            const long boff = (long)(nt * 16 + lr) * 256 + ks * 32 + lg * 8;
            const s16x8 bh = *(const s16x8*)(wu_hi + boff);
            const s16x8 bl = *(const s16x8*)(wu_lo + boff);
            #pragma unroll
            for (int tt = 0; tt < 2; ++tt) {
                acc[tt] = __builtin_amdgcn_mfma_f32_16x16x32_bf16(al[tt][ks], bh, acc[tt], 0, 0, 0);
                acc[tt] = __builtin_amdgcn_mfma_f32_16x16x32_bf16(ah[tt][ks], bl, acc[tt], 0, 0, 0);
                acc[tt] = __builtin_amdgcn_mfma_f32_16x16x32_bf16(ah[tt][ks], bh, acc[tt], 0, 0, 0);
            }
        }
        #pragma unroll
        for (int tt = 0; tt < 2; ++tt)
            #pragma unroll
            for (int r = 0; r < 4; ++r)
                C[(long)(t0 + tt * 16 + lg * 4 + r) * 512 + nt * 16 + lr] = acc[tt][r];
    }
}

// ---------------------------------------------------------------------------
// Scale summed losses by 1/(4096*256) and write both loss outputs.
// ---------------------------------------------------------------------------
__global__ void finalize_kernel(const float* __restrict__ loss_acc,
                                float* __restrict__ out_losses) {
    int i = threadIdx.x;
    if (i < 16) {
        float v = loss_acc[i] * (1.0f / 1048576.0f);
        out_losses[i]      = v;   // commitment_loss
        out_losses[16 + i] = v;   // codebook_loss (same forward value)
    }
}

// ---------------------------------------------------------------------------
extern "C" void kernel_launch(void* const* d_in, const int* in_sizes, int n_in,
                              void* d_out, int out_size, void* d_ws, size_t ws_size,
                              hipStream_t stream) {
    const float* z      = (const float*)d_in[0];  // [16,4096,512]
    const float* cb     = (const float*)d_in[1];  // [1024,256]
    const float* w_down = (const float*)d_in[2];  // [256,512]
    const float* w_up   = (const float*)d_in[3];  // [512,256]

    float* out        = (float*)d_out;
    float* z_out      = out;                       // 33554432 floats
    float* out_losses = out + 33554432;            // 16 + 16 floats
    float* code_f     = out + 33554464;            // 65536 floats

    // z_e interleaved planes (hi<<16|lo, 64 MiB) live inside the not-yet-
    // written z_out region; fully consumed by argmin before gemm_up writes.
    unsigned* ze_il = (unsigned*)d_out;

    char* ws = (char*)d_ws;
    unsigned short* cb_hi = (unsigned short*)(ws);             // 512 KiB
    unsigned short* cb_lo = (unsigned short*)(ws + 524288);    // 512 KiB
    unsigned short* wu_hi = (unsigned short*)(ws + 1048576);   // 256 KiB
    unsigned short* wu_lo = (unsigned short*)(ws + 1310720);   // 256 KiB
    unsigned short* wd_hi = (unsigned short*)(ws + 1572864);   // 256 KiB
    unsigned short* wd_lo = (unsigned short*)(ws + 1835008);   // 256 KiB
    int*   code_i    = (int*)  (ws + 2097152);                 // 256 KiB
    float* cnorm     = (float*)(ws + 2359296);                 // 4 KiB
    float* znorm     = (float*)(ws + 2363392);                 // 256 KiB
    int4*  flag_list = (int4*) (ws + 2625536);                 // 256 KiB
    int4*  pair_buf  = (int4*) (ws + 2887680);                 // 2 MiB (2 x 65536 x 16B)
    float* loss_acc  = (float*)(ws + 4984832);                 // 64 B
    int*   flag_cnt  = (int*)  (ws + 4984896);                 // 4 B

    hipMemsetAsync(ws + 4984832, 0, 128, stream);

    // codebook row norms (fp32)
    rownorm_kernel<<<NCODES / 4, 256, 0, stream>>>(cb, cnorm);

    // bf16 hi/lo planes of codebook, w_up, w_down
    split_kernel<<<1024, 256, 0, stream>>>(cb, cb_hi, cb_lo, NCODES * D_E);
    split_kernel<<<512, 256, 0, stream>>>(w_up, wu_hi, wu_lo, D_IN * D_E);
    split_kernel<<<512, 256, 0, stream>>>(w_down, wd_hi, wd_lo, D_E * D_IN);

    // GEMM1 (MFMA bf16x3): z_e = z @ w_down^T, emits interleaved planes + znorm
    gemm_down_mfma_kernel<<<TOKS / 128, 256, 0, stream>>>(
        z, wd_hi, wd_lo, ze_il, znorm);

    // distances + per-half top-2 via MFMA bf16x3 (code-split x2 for occupancy)
    argmin_mfma_kernel<<<(TOKS / 128) * 2, 256, 0, stream>>>(
        ze_il, cb_hi, cb_lo, cnorm, pair_buf);

    // merge halves; write code/loss; flag near-ties
    merge_kernel<<<TOKS / 256, 256, 0, stream>>>(
        pair_buf, znorm, code_i, code_f, loss_acc, flag_cnt, flag_list);

    // exact fp32 re-decision for near-tie tokens
    refine_kernel<<<256, 256, 0, stream>>>(z, w_down, cb, flag_cnt, flag_list,
                                           code_i, code_f, loss_acc);

    // GEMM2 (MFMA bf16x3, gathered): z_out = cb[code] @ w_up^T
    gemm_up_mfma_kernel<<<TOKS / 128, 256, 0, stream>>>(
        cb_hi, cb_lo, wu_hi, wu_lo, code_i, z_out);

    finalize_kernel<<<1, 64, 0, stream>>>(loss_acc, out_losses);
}

// Round 4
// 505.933 us; speedup vs baseline: 1.3644x; 1.3644x over previous
//
#include <hip/hip_runtime.h>

// Problem dims
#define TOKS    65536      // 16 * 4096
#define D_IN    512
#define D_E     256
#define NCODES  1024

#define FLAG_CAP 16384
#define TAU      0.05f     // gap threshold for fp32 refinement (~60 sigma of approx err)

using s16x8 = __attribute__((ext_vector_type(8))) short;   // 8 bf16 = 4 VGPRs
using f32x4 = __attribute__((ext_vector_type(4))) float;   // MFMA 16x16 accumulator

__device__ __forceinline__ unsigned short bf16_rne(float x) {
    unsigned u = __float_as_uint(x);
    u += 0x7fffu + ((u >> 16) & 1u);
    return (unsigned short)(u >> 16);
}
__device__ __forceinline__ float bf16_to_f(unsigned short h) {
    return __uint_as_float(((unsigned)h) << 16);
}

// Unpack 8 interleaved (hi<<16|lo) words into separate hi/lo bf16x8 fragments.
__device__ __forceinline__ void unpack_il(uint4 u0, uint4 u1, s16x8& hi, s16x8& lo) {
    union { unsigned u[4]; s16x8 v; } H, L;
    H.u[0] = (u0.y & 0xffff0000u) | (u0.x >> 16);
    H.u[1] = (u0.w & 0xffff0000u) | (u0.z >> 16);
    H.u[2] = (u1.y & 0xffff0000u) | (u1.x >> 16);
    H.u[3] = (u1.w & 0xffff0000u) | (u1.z >> 16);
    L.u[0] = (u0.y << 16) | (u0.x & 0xffffu);
    L.u[1] = (u0.w << 16) | (u0.z & 0xffffu);
    L.u[2] = (u1.y << 16) | (u1.x & 0xffffu);
    L.u[3] = (u1.w << 16) | (u1.z & 0xffffu);
    hi = H.v; lo = L.v;
}

// ---------------------------------------------------------------------------
// Row squared-norm on fp32 rows of 256 (codebook -> cnorm). One wave/row.
// ---------------------------------------------------------------------------
__global__ __launch_bounds__(256) void rownorm_kernel(
        const float* __restrict__ src, float* __restrict__ dst) {
    int row  = blockIdx.x * 4 + (threadIdx.x >> 6);
    int lane = threadIdx.x & 63;
    float4 v = *(const float4*)(src + (long)row * 256 + lane * 4);
    float s = v.x * v.x + v.y * v.y + v.z * v.z + v.w * v.w;
    #pragma unroll
    for (int off = 32; off; off >>= 1) s += __shfl_xor(s, off, 64);
    if (lane == 0) dst[row] = s;
}

// ---------------------------------------------------------------------------
// fp32 -> (hi, lo) bf16 planes. hi = rne(x), lo = rne(x - hi): x to ~2^-17 rel.
// ---------------------------------------------------------------------------
__global__ __launch_bounds__(256) void split_kernel(
        const float* __restrict__ src, unsigned short* __restrict__ hi,
        unsigned short* __restrict__ lo, int n) {
    int i = blockIdx.x * 256 + threadIdx.x;
    if (i < n) {
        float x = src[i];
        unsigned short hb = bf16_rne(x);
        hi[i] = hb;
        lo[i] = bf16_rne(x - bf16_to_f(hb));
    }
}

// ---------------------------------------------------------------------------
// cb_up = cb @ w_up^T in EXACT fp32: [1024,256] x [512,256]^T -> [1024,512].
// One block per 4 cb rows (grid 256); cb rows staged in LDS (broadcast reads);
// thread t owns output cols t and t+256, streaming w_up rows via float4.
// ---------------------------------------------------------------------------
__global__ __launch_bounds__(256) void cb_up_kernel(
        const float* __restrict__ cb, const float* __restrict__ w_up,
        float* __restrict__ cb_up) {
    __shared__ float cbs4[4][256];
    const int tid = threadIdx.x;
    const int r0  = blockIdx.x * 4;
    #pragma unroll
    for (int r = 0; r < 4; ++r) cbs4[r][tid] = cb[(long)(r0 + r) * 256 + tid];
    __syncthreads();
    float acc[4][2] = {};
    const float* wa = w_up + (long)tid * 256;
    const float* wb = w_up + (long)(tid + 256) * 256;
    #pragma unroll 4
    for (int k = 0; k < 256; k += 4) {
        float4 a = *(const float4*)(wa + k);
        float4 b = *(const float4*)(wb + k);
        #pragma unroll
        for (int r = 0; r < 4; ++r) {
            float4 c = *(const float4*)&cbs4[r][k];
            acc[r][0] += a.x * c.x + a.y * c.y + a.z * c.z + a.w * c.w;
            acc[r][1] += b.x * c.x + b.y * c.y + b.z * c.z + b.w * c.w;
        }
    }
    #pragma unroll
    for (int r = 0; r < 4; ++r) {
        cb_up[(long)(r0 + r) * 512 + tid]       = acc[r][0];
        cb_up[(long)(r0 + r) * 512 + tid + 256] = acc[r][1];
    }
}

// ---------------------------------------------------------------------------
// z_out[tok] = cb_up[code[tok]] : pure gather, HBM-write-bound (~128 MB).
// Coalesced float4 writes; table reads are 1 KB contiguous runs from L2.
// ---------------------------------------------------------------------------
__global__ __launch_bounds__(256) void gather_kernel(
        const float4* __restrict__ cb_up4, const int* __restrict__ code_i,
        float4* __restrict__ out4) {
    const int base = blockIdx.x * 1024 + threadIdx.x;
    #pragma unroll
    for (int j = 0; j < 4; ++j) {
        int g   = base + j * 256;
        int tok = g >> 7;          // 128 float4 per 512-float row
        int col = g & 127;
        out4[g] = cb_up4[(long)code_i[tok] * 128 + col];
    }
}

// ---------------------------------------------------------------------------
// GEMM1 via bf16x3 MFMA: z_e = z @ w_down^T  [65536,512] x [256,512]^T.
// Block = 256 thr / 4 waves, 128 tokens (32/wave as 2 token-tiles of 16).
// w_down planes LDS-staged per 32-k step, double-buffered, 1 barrier/step:
//   - staging: unit j = i*256+tid; consecutive lanes -> consecutive 16B in
//     LDS (b128-write floor) and 64B global runs (coalesced, L2-resident).
//   - reads: [plane][n][32k] rows of 64 B -> (n*4+lg) mod 8 quad = b128 floor.
// z (fp32, HBM, read once) split hi/lo bf16 in-register (exact-trunc hi).
// Epilogue: interleaved z_e planes (hi<<16|lo) + fused znorm.
// ---------------------------------------------------------------------------
__global__ __launch_bounds__(256, 2) void gemm_down_mfma_kernel(
        const float* __restrict__ z, const unsigned short* __restrict__ wd_hi,
        const unsigned short* __restrict__ wd_lo, unsigned* __restrict__ ze_il,
        float* __restrict__ znorm) {
    __shared__ __align__(16) unsigned short wds[2][2][256][32];   // 2 x 32 KB

    const int tid  = threadIdx.x;
    const int w    = tid >> 6;
    const int lane = tid & 63;
    const int lr   = lane & 15;
    const int lg   = lane >> 4;
    const int t0   = blockIdx.x * 128 + w * 32;

    f32x4 acc[2][16] = {};   // [token-tile][n-tile]

    auto stage = [&](int b, int ks) {
        #pragma unroll
        for (int i = 0; i < 8; ++i) {
            const int j = i * 256 + tid;          // 2048 units of 16 B
            const int p = j >> 10, rw = (j >> 2) & 255, sub = j & 3;
            const s16x8 v = *(const s16x8*)((p ? wd_lo : wd_hi)
                                            + (long)rw * 512 + ks * 32 + sub * 8);
            *(s16x8*)((unsigned short*)wds[b] + j * 8) = v;
        }
    };

    stage(0, 0);

    #pragma unroll 1
    for (int ks = 0; ks < 16; ++ks) {        // K = 512 in steps of 32
        const int b = ks & 1;
        __syncthreads();                      // staging of buf b complete
        if (ks < 15) stage(b ^ 1, ks + 1);    // prefetch next step

        // A fragments: z fp32 -> hi (exact truncation) + lo (rne of remainder)
        s16x8 ah[2], al[2];
        #pragma unroll
        for (int tt = 0; tt < 2; ++tt) {
            const float* zp = z + (long)(t0 + tt * 16 + lr) * 512 + ks * 32 + lg * 8;
            float4 x0 = *(const float4*)zp;
            float4 x1 = *(const float4*)(zp + 4);
            float xs[8] = {x0.x, x0.y, x0.z, x0.w, x1.x, x1.y, x1.z, x1.w};
            #pragma unroll
            for (int j = 0; j < 8; ++j) {
                unsigned hb = __float_as_uint(xs[j]) & 0xffff0000u;
                float rem = xs[j] - __uint_as_float(hb);
                ah[tt][j] = (short)(hb >> 16);
                al[tt][j] = (short)bf16_rne(rem);
            }
        }

        #pragma unroll
        for (int nt = 0; nt < 16; ++nt) {
            const s16x8 bh = *(const s16x8*)&wds[b][0][nt * 16 + lr][lg * 8];
            const s16x8 bl = *(const s16x8*)&wds[b][1][nt * 16 + lr][lg * 8];
            #pragma unroll
            for (int tt = 0; tt < 2; ++tt) {
                acc[tt][nt] = __builtin_amdgcn_mfma_f32_16x16x32_bf16(al[tt], bh, acc[tt][nt], 0, 0, 0);
                acc[tt][nt] = __builtin_amdgcn_mfma_f32_16x16x32_bf16(ah[tt], bl, acc[tt][nt], 0, 0, 0);
                acc[tt][nt] = __builtin_amdgcn_mfma_f32_16x16x32_bf16(ah[tt], bh, acc[tt][nt], 0, 0, 0);
            }
        }
    }

    // ---- epilogue: interleaved plane write + fused znorm ----
    #pragma unroll
    for (int tt = 0; tt < 2; ++tt) {
        float ns[4] = {0.f, 0.f, 0.f, 0.f};
        #pragma unroll
        for (int nt = 0; nt < 16; ++nt)
            #pragma unroll
            for (int r = 0; r < 4; ++r) {
                float x = acc[tt][nt][r];
                ns[r] += x * x;
                unsigned short hb = bf16_rne(x);
                unsigned short lb = bf16_rne(x - bf16_to_f(hb));
                ze_il[(long)(t0 + tt * 16 + lg * 4 + r) * 256 + nt * 16 + lr] =
                    ((unsigned)hb << 16) | lb;
            }
        #pragma unroll
        for (int r = 0; r < 4; ++r) {
            float s = ns[r];
            s += __shfl_xor(s, 1, 64);
            s += __shfl_xor(s, 2, 64);
            s += __shfl_xor(s, 4, 64);
            s += __shfl_xor(s, 8, 64);
            if (lr == 0) znorm[t0 + tt * 16 + lg * 4 + r] = s;
        }
    }
}

// ---------------------------------------------------------------------------
// Fused distance + argmin via bf16x3 MFMA (16x16x32). SINGLE PASS (1024
// codes/block): z_e read once into full-K register fragments; codebook
// chunks (64 codes x 128 k) staged in LDS with padded row stride 136 shorts
// (b128 conflict floor, static offsets). Top-2 tracking; near-ties flagged.
// ---------------------------------------------------------------------------
__global__ __launch_bounds__(256, 2) void argmin_mfma_kernel(
        const unsigned* __restrict__ ze_il,
        const unsigned short* __restrict__ cb_hi, const unsigned short* __restrict__ cb_lo,
        const float* __restrict__ cnorm, const float* __restrict__ znorm,
        int* __restrict__ code_i, float* __restrict__ code_f,
        float* __restrict__ loss_acc, int* __restrict__ flag_cnt,
        int4* __restrict__ flag_list) {
    __shared__ __align__(16) unsigned short cbs[2][64][136];   // 34 KB, padded stride

    const int tid  = threadIdx.x;
    const int w    = tid >> 6;
    const int lane = tid & 63;
    const int lr   = lane & 15;      // row/col within 16-tile
    const int lg   = lane >> 4;      // k-group (0..3)
    const int t0   = blockIdx.x * 128;

    // ---- load A fragments once: 2 token-tiles x 8 k-steps x {hi,lo} ----
    s16x8 ah[2][8], al[2][8];
    {
        const int tokA = t0 + w * 32 + lr;
        #pragma unroll
        for (int tt = 0; tt < 2; ++tt) {
            const unsigned* pz = ze_il + (long)(tokA + tt * 16) * 256 + lg * 8;
            #pragma unroll
            for (int ks = 0; ks < 8; ++ks) {
                uint4 u0 = *(const uint4*)(pz + ks * 32);
                uint4 u1 = *(const uint4*)(pz + ks * 32 + 4);
                unpack_il(u0, u1, ah[tt][ks], al[tt][ks]);
            }
        }
    }

    const int lane_base = lr * 136 + lg * 8;   // shorts; rest static offsets

    float d1[8], d2[8];
    int   i1[8], i2[8];
    #pragma unroll
    for (int s = 0; s < 8; ++s) { d1[s] = 3.4e38f; d2[s] = 3.4e38f; i1[s] = 0; i2[s] = 0; }

    #pragma unroll 1
    for (int c = 0; c < 16; ++c) {           // 64-code chunks
        const int c0 = c * 64;
        f32x4 acc[2][4] = {};

        #pragma unroll
        for (int kc = 0; kc < 2; ++kc) {     // 128-k chunks
            __syncthreads();
            {   // stage cb chunk: wave-pair q picks plane, half the 16B units
                const int r = tid & 63, q = tid >> 6;
                const unsigned short* src = (q & 2 ? cb_lo : cb_hi)
                                            + (c0 + r) * 256 + kc * 128 + (q & 1) * 64;
                unsigned short* dst = &cbs[q >> 1][r][0] + (q & 1) * 64;
                #pragma unroll
                for (int i = 0; i < 8; ++i)
                    *(s16x8*)(dst + i * 8) = *(const s16x8*)(src + i * 8);
            }
            __syncthreads();

            #pragma unroll
            for (int k4 = 0; k4 < 4; ++k4) {
                const int ks = kc * 4 + k4;                 // A reg index (static)
                #pragma unroll
                for (int nt = 0; nt < 4; ++nt) {
                    const int off = lane_base + nt * 2176 + k4 * 32;   // shorts
                    const s16x8 bh = *(const s16x8*)(&cbs[0][0][0] + off);
                    const s16x8 bl = *(const s16x8*)(&cbs[1][0][0] + off);
                    #pragma unroll
                    for (int tt = 0; tt < 2; ++tt) {
                        acc[tt][nt] = __builtin_amdgcn_mfma_f32_16x16x32_bf16(al[tt][ks], bh, acc[tt][nt], 0, 0, 0);
                        acc[tt][nt] = __builtin_amdgcn_mfma_f32_16x16x32_bf16(ah[tt][ks], bl, acc[tt][nt], 0, 0, 0);
                        acc[tt][nt] = __builtin_amdgcn_mfma_f32_16x16x32_bf16(ah[tt][ks], bh, acc[tt][nt], 0, 0, 0);
                    }
                }
            }
        }

        // ---- fold chunk into running top-2 (codes ascend -> strict < keeps first) ----
        #pragma unroll
        for (int nt = 0; nt < 4; ++nt) {
            const int idx = c0 + nt * 16 + lr;
            const float cn = cnorm[idx];
            #pragma unroll
            for (int tt = 0; tt < 2; ++tt)
                #pragma unroll
                for (int r = 0; r < 4; ++r) {
                    float d = cn - 2.0f * acc[tt][nt][r];
                    const int s = tt * 4 + r;
                    if (d < d1[s])      { d2[s] = d1[s]; i2[s] = i1[s]; d1[s] = d; i1[s] = idx; }
                    else if (d < d2[s]) { d2[s] = d;     i2[s] = idx; }
                }
        }
    }

    // ---- cross-lane top-2 merge over the 16 code columns ----
    #pragma unroll
    for (int off = 1; off <= 8; off <<= 1) {
        #pragma unroll
        for (int s = 0; s < 8; ++s) {
            float od1 = __shfl_xor(d1[s], off, 64);
            int   oi1 = __shfl_xor(i1[s], off, 64);
            float od2 = __shfl_xor(d2[s], off, 64);
            int   oi2 = __shfl_xor(i2[s], off, 64);
            bool take = (od1 < d1[s]) || (od1 == d1[s] && oi1 < i1[s]);
            float w1 = take ? od1 : d1[s];  int wi1 = take ? oi1 : i1[s];
            float l1 = take ? d1[s] : od1;  int li1 = take ? i1[s] : oi1;   // loser of firsts
            float w2 = take ? od2 : d2[s];  int wi2 = take ? oi2 : i2[s];   // winner's second
            bool t2 = (l1 < w2) || (l1 == w2 && li1 < wi2);
            d1[s] = w1; i1[s] = wi1;
            d2[s] = t2 ? l1 : w2;
            i2[s] = t2 ? li1 : wi2;
        }
    }

    // ---- write: lanes lr==0 own tokens (w*32 + tt*16 + lg*4 + r) ----
    if (lr == 0) {
        float lsum = 0.0f;
        #pragma unroll
        for (int s = 0; s < 8; ++s) {
            const int tok = t0 + w * 32 + (s >> 2) * 16 + lg * 4 + (s & 3);
            code_i[tok] = i1[s];
            code_f[tok] = (float)i1[s];
            const float rec = d1[s] + znorm[tok];
            lsum += rec;
            if (d2[s] - d1[s] < TAU) {
                int slot = atomicAdd(flag_cnt, 1);
                if (slot < FLAG_CAP)
                    flag_list[slot] = make_int4(tok, i1[s], i2[s], __float_as_int(rec));
            }
        }
        atomicAdd(loss_acc + (t0 >> 12), lsum);   // 128-tok block never straddles a batch
    }
}

// ---------------------------------------------------------------------------
// Exact fp32 refinement for near-tie tokens: recompute z_e row from z@w_down
// in fp32, re-decide best-of-two with first-index tie-break, patch loss.
// ---------------------------------------------------------------------------
__global__ __launch_bounds__(256) void refine_kernel(
        const float* __restrict__ z, const float* __restrict__ w_down,
        const float* __restrict__ cb, const int* __restrict__ flag_cnt,
        const int4* __restrict__ flag_list, int* __restrict__ code_i,
        float* __restrict__ code_f, float* __restrict__ loss_acc) {
    __shared__ float zrow[512];
    __shared__ float redA[4], redB[4];
    const int tid = threadIdx.x;
    int n = *flag_cnt;
    if (n > FLAG_CAP) n = FLAG_CAP;

    for (int it = blockIdx.x; it < n; it += gridDim.x) {
        const int4 f = flag_list[it];
        const int tok = f.x, ia = f.y, ib = f.z;
        __syncthreads();
        zrow[tid]       = z[(long)tok * 512 + tid];
        zrow[tid + 256] = z[(long)tok * 512 + 256 + tid];
        __syncthreads();

        // thread e computes z_e[e] = dot(w_down[e], zrow) in fp32
        float s = 0.0f;
        const float* wr = w_down + (long)tid * 512;
        #pragma unroll 4
        for (int k = 0; k < 512; k += 4) {
            float4 a = *(const float4*)(wr + k);
            s += a.x * zrow[k] + a.y * zrow[k + 1] + a.z * zrow[k + 2] + a.w * zrow[k + 3];
        }
        float da = s - cb[(long)ia * 256 + tid]; da *= da;
        float db = s - cb[(long)ib * 256 + tid]; db *= db;
        #pragma unroll
        for (int off = 32; off; off >>= 1) {
            da += __shfl_xor(da, off, 64);
            db += __shfl_xor(db, off, 64);
        }
        if ((tid & 63) == 0) { redA[tid >> 6] = da; redB[tid >> 6] = db; }
        __syncthreads();
        if (tid == 0) {
            float ea = redA[0] + redA[1] + redA[2] + redA[3];
            float eb = redB[0] + redB[1] + redB[2] + redB[3];
            float ebest = ea; int ibest = ia;
            if (eb < ea || (eb == ea && ib < ia)) { ebest = eb; ibest = ib; }
            if (ibest != ia) { code_i[tok] = ibest; code_f[tok] = (float)ibest; }
            atomicAdd(loss_acc + (tok >> 12), ebest - __int_as_float(f.w));
        }
    }
}

// ---------------------------------------------------------------------------
// Scale summed losses by 1/(4096*256) and write both loss outputs.
// ---------------------------------------------------------------------------
__global__ void finalize_kernel(const float* __restrict__ loss_acc,
                                float* __restrict__ out_losses) {
    int i = threadIdx.x;
    if (i < 16) {
        float v = loss_acc[i] * (1.0f / 1048576.0f);
        out_losses[i]      = v;   // commitment_loss
        out_losses[16 + i] = v;   // codebook_loss (same forward value)
    }
}

// ---------------------------------------------------------------------------
extern "C" void kernel_launch(void* const* d_in, const int* in_sizes, int n_in,
                              void* d_out, int out_size, void* d_ws, size_t ws_size,
                              hipStream_t stream) {
    const float* z      = (const float*)d_in[0];  // [16,4096,512]
    const float* cb     = (const float*)d_in[1];  // [1024,256]
    const float* w_down = (const float*)d_in[2];  // [256,512]
    const float* w_up   = (const float*)d_in[3];  // [512,256]

    float* out        = (float*)d_out;
    float* z_out      = out;                       // 33554432 floats
    float* out_losses = out + 33554432;            // 16 + 16 floats
    float* code_f     = out + 33554464;            // 65536 floats

    // z_e interleaved planes (hi<<16|lo, 64 MiB) live inside the not-yet-
    // written z_out region; fully consumed by argmin before gather writes.
    unsigned* ze_il = (unsigned*)d_out;

    char* ws = (char*)d_ws;
    unsigned short* cb_hi = (unsigned short*)(ws);             // 512 KiB
    unsigned short* cb_lo = (unsigned short*)(ws + 524288);    // 512 KiB
    unsigned short* wd_hi = (unsigned short*)(ws + 1048576);   // 256 KiB
    unsigned short* wd_lo = (unsigned short*)(ws + 1310720);   // 256 KiB
    int*   code_i    = (int*)  (ws + 1572864);                 // 256 KiB
    float* cnorm     = (float*)(ws + 1835008);                 // 4 KiB
    float* znorm     = (float*)(ws + 1839104);                 // 256 KiB
    int4*  flag_list = (int4*) (ws + 2101248);                 // 256 KiB
    float* cb_up     = (float*)(ws + 2363392);                 // 2 MiB
    float* loss_acc  = (float*)(ws + 4460544);                 // 64 B
    int*   flag_cnt  = (int*)  (ws + 4460608);                 // 4 B

    hipMemsetAsync(ws + 4460544, 0, 128, stream);

    // codebook row norms (fp32)
    rownorm_kernel<<<NCODES / 4, 256, 0, stream>>>(cb, cnorm);

    // bf16 hi/lo planes of codebook and w_down
    split_kernel<<<1024, 256, 0, stream>>>(cb, cb_hi, cb_lo, NCODES * D_E);
    split_kernel<<<512, 256, 0, stream>>>(w_down, wd_hi, wd_lo, D_E * D_IN);

    // exact fp32 up-projection of the whole codebook (replaces GEMM2!)
    cb_up_kernel<<<NCODES / 4, 256, 0, stream>>>(cb, w_up, cb_up);

    // GEMM1 (MFMA bf16x3, LDS-staged B): z_e planes + fused znorm
    gemm_down_mfma_kernel<<<TOKS / 128, 256, 0, stream>>>(
        z, wd_hi, wd_lo, ze_il, znorm);

    // distances + argmin + losses via MFMA bf16x3 (single pass, padded LDS)
    argmin_mfma_kernel<<<TOKS / 128, 256, 0, stream>>>(
        ze_il, cb_hi, cb_lo, cnorm, znorm, code_i, code_f, loss_acc,
        flag_cnt, flag_list);

    // exact fp32 re-decision for near-tie tokens
    refine_kernel<<<256, 256, 0, stream>>>(z, w_down, cb, flag_cnt, flag_list,
                                           code_i, code_f, loss_acc);

    // z_out = cb_up[code] : pure gather, write-bound
    gather_kernel<<<TOKS * 512 / 4 / 1024, 256, 0, stream>>>(
        (const float4*)cb_up, code_i, (float4*)z_out);

    finalize_kernel<<<1, 64, 0, stream>>>(loss_acc, out_losses);
}